// Round 1
// 1786.921 us; speedup vs baseline: 1.0219x; 1.0219x over previous
//
#include <hip/hip_runtime.h>
#include <math.h>

typedef unsigned short u16;
typedef unsigned int u32;
typedef __attribute__((ext_vector_type(8))) short short8;
typedef __attribute__((ext_vector_type(4))) float floatx4;

// ---------------- problem constants ----------------
#define BB 64
#define NTOK 197
#define NPATCH 196
#define EMB 192
#define NH 3
#define HD 64
#define FEAT 256
#define MLPD 768
#define NCLS 1000
#define MTOT (BB*NTOK)      // 12608
#define MPAT (BB*NPATCH)    // 12544
#define BHT (BB*NH)         // 192

// ---------------- bf16 helpers ----------------
__device__ __forceinline__ u16 f2bf(float x) {
    u32 u = __builtin_bit_cast(u32, x);
    u32 r = u + 0x7FFFu + ((u >> 16) & 1u);
    return (u16)(r >> 16);
}
__device__ __forceinline__ float bf2f(u16 u) {
    return __builtin_bit_cast(float, (u32)u << 16);
}
__device__ __forceinline__ float sqr8bf(uint4 v) {
    float s = 0.f;
    float t;
    t = bf2f((u16)(v.x & 0xffff)); s += t*t;  t = bf2f((u16)(v.x >> 16)); s += t*t;
    t = bf2f((u16)(v.y & 0xffff)); s += t*t;  t = bf2f((u16)(v.y >> 16)); s += t*t;
    t = bf2f((u16)(v.z & 0xffff)); s += t*t;  t = bf2f((u16)(v.z >> 16)); s += t*t;
    t = bf2f((u16)(v.w & 0xffff)); s += t*t;  t = bf2f((u16)(v.w >> 16)); s += t*t;
    return s;
}

// ---------------- weight prep ----------------
__global__ void cvt_bf16(const float* __restrict__ in, u16* __restrict__ out, int n)
{
    const int i = blockIdx.x * 256 + threadIdx.x;
    if (i < n) out[i] = f2bf(in[i]);
}

// in [L][R][C] fp32 -> out [L][C][R] bf16
__global__ void tr_bf16(const float* __restrict__ in, u16* __restrict__ out,
                        int R, int C, int total)
{
    const int i = blockIdx.x * 256 + threadIdx.x;
    if (i >= total) return;
    const int r = i % R;
    const int c = (i / R) % C;
    const int l = i / (R * C);
    out[i] = f2bf(in[((size_t)l * R + r) * C + c]);
}

// ================= MFMA bf16 GEMM =================
// C[M,N] = A[M,K] @ Bt[N,K]^T + bias
// mode 0: fp32 out ; mode 1: fp32 out + res ; mode 2: gelu -> bf16 out ; mode 3: bf16 out
__global__ __launch_bounds__(256) void gemm_bf16(
    const u16* __restrict__ A, const u16* __restrict__ Bt,
    const float* __restrict__ bias, const float* __restrict__ res,
    float* __restrict__ Cf, u16* __restrict__ Cb,
    int M, int N, int K, int mode)
{
    __shared__ u16 As[64][72];
    __shared__ u16 Bs[64][72];
    const int tid = threadIdx.x;
    const int lane = tid & 63, wave = tid >> 6;
    const int wr = wave & 1, wc = wave >> 1;
    const int l16 = lane & 15, quad = lane >> 4;
    const int m0 = blockIdx.y * 64, n0 = blockIdx.x * 64;
    const int srow = tid >> 2, skof = (tid & 3) * 16;

    floatx4 acc00 = {0.f,0.f,0.f,0.f}, acc01 = {0.f,0.f,0.f,0.f};
    floatx4 acc10 = {0.f,0.f,0.f,0.f}, acc11 = {0.f,0.f,0.f,0.f};

    const int gmA = m0 + srow;
    const bool mok = (gmA < M);
    const u16* ap = A + (size_t)gmA * K + skof;
    const u16* bp = Bt + (size_t)(n0 + srow) * K + skof;

    for (int k0 = 0; k0 < K; k0 += 64) {
        uint4 a0 = {0,0,0,0}, a1 = {0,0,0,0};
        if (mok) { a0 = *(const uint4*)(ap + k0); a1 = *(const uint4*)(ap + k0 + 8); }
        const uint4 b0 = *(const uint4*)(bp + k0);
        const uint4 b1 = *(const uint4*)(bp + k0 + 8);
        if (k0) __syncthreads();
        *(uint4*)&As[srow][skof]     = a0;
        *(uint4*)&As[srow][skof + 8] = a1;
        *(uint4*)&Bs[srow][skof]     = b0;
        *(uint4*)&Bs[srow][skof + 8] = b1;
        __syncthreads();
#pragma unroll
        for (int ks = 0; ks < 2; ++ks) {
            const short8 af0 = *(const short8*)&As[wr*32 + l16][ks*32 + quad*8];
            const short8 af1 = *(const short8*)&As[wr*32 + 16 + l16][ks*32 + quad*8];
            const short8 bf0 = *(const short8*)&Bs[wc*32 + l16][ks*32 + quad*8];
            const short8 bf1 = *(const short8*)&Bs[wc*32 + 16 + l16][ks*32 + quad*8];
            acc00 = __builtin_amdgcn_mfma_f32_16x16x32_bf16(af0, bf0, acc00, 0, 0, 0);
            acc01 = __builtin_amdgcn_mfma_f32_16x16x32_bf16(af0, bf1, acc01, 0, 0, 0);
            acc10 = __builtin_amdgcn_mfma_f32_16x16x32_bf16(af1, bf0, acc10, 0, 0, 0);
            acc11 = __builtin_amdgcn_mfma_f32_16x16x32_bf16(af1, bf1, acc11, 0, 0, 0);
        }
    }

    floatx4 accs[2][2] = {{acc00, acc01}, {acc10, acc11}};
    const int rbase = m0 + wr * 32 + quad * 4;
    const int cbase = n0 + wc * 32 + l16;
#pragma unroll
    for (int r = 0; r < 2; ++r) {
#pragma unroll
        for (int reg = 0; reg < 4; ++reg) {
            const int gm = rbase + r * 16 + reg;
            if (gm >= M) continue;
#pragma unroll
            for (int c = 0; c < 2; ++c) {
                const int gn = cbase + c * 16;
                float v = accs[r][c][reg] + bias[gn];
                if (mode == 1) v += res[(size_t)gm * N + gn];
                if (mode == 2) {
                    v = 0.5f * v * (1.f + erff(v * 0.70710678118654752f));
                    Cb[(size_t)gm * N + gn] = f2bf(v);
                } else if (mode == 3) {
                    Cb[(size_t)gm * N + gn] = f2bf(v);
                } else {
                    Cf[(size_t)gm * N + gn] = v;
                }
            }
        }
    }
}

// ================= fused performer attention, stage 1 =====================
// Per (b,h): pk[n][f] = exp(k_n . pm_f - |k_n|^2/2)*s ; ksum[f] = sum_n pk ;
// kvT[d][f] = sum_n v[n][d]*pk[n][f].  All intermediates stay in LDS.
__global__ __launch_bounds__(256) void attn_pkv(
    const u16* __restrict__ qkv, const u16* __restrict__ pmb,
    u16* __restrict__ kvT, float* __restrict__ ksum)
{
    __shared__ u16 pm_s[256][72];     // [f][d]
    __shared__ u16 kt_s[64][72];      // [n][d] tile
    __shared__ u16 vT_s[64][72];      // [d][n] tile
    __shared__ u16 pkT_s[256][72];    // [f][n] tile
    __shared__ float nrm_s[64];
    __shared__ float ksum_s[256];

    const int tid = threadIdx.x;
    const int lane = tid & 63, wave = tid >> 6;
    const int l16 = lane & 15, quad = lane >> 4;
    const int bh = blockIdx.x, b = bh / NH, h = bh % NH;
    const int fbase = wave * 64;
    const int srow = tid >> 2, skof = (tid & 3) * 16;
    const float scale = 0.35355339059327373f;

    // pm -> LDS (once): 256x64 bf16
#pragma unroll
    for (int j = 0; j < 8; ++j) {
        const int flat = j * 256 + tid;
        const int f = flat >> 3, o = (flat & 7) * 8;
        *(uint4*)&pm_s[f][o] = *(const uint4*)(pmb + f * 64 + o);
    }
    ksum_s[tid] = 0.f;

    floatx4 kv[4][4];
#pragma unroll
    for (int i = 0; i < 4; ++i)
#pragma unroll
        for (int j = 0; j < 4; ++j) kv[i][j] = (floatx4){0.f,0.f,0.f,0.f};

    // stage tile 0 k/v into regs
    uint4 k0v = {0,0,0,0}, k1v = {0,0,0,0}, v0v = {0,0,0,0}, v1v = {0,0,0,0};
    {
        const u16* kp = qkv + ((size_t)(b * NTOK + srow)) * 576 + 192 + h * 64 + skof;
        k0v = *(const uint4*)kp; k1v = *(const uint4*)(kp + 8);
        v0v = *(const uint4*)(kp + 192); v1v = *(const uint4*)(kp + 200);
    }

    for (int t = 0; t < 4; ++t) {
        const int ncur = t * 64 + srow;
        if (t) __syncthreads();                    // prev-tile MFMA done with LDS
        // staged regs -> LDS
        *(uint4*)&kt_s[srow][skof]     = k0v;
        *(uint4*)&kt_s[srow][skof + 8] = k1v;
        {
            u16 vv[16];
            vv[0]=(u16)(v0v.x&0xffff);  vv[1]=(u16)(v0v.x>>16);
            vv[2]=(u16)(v0v.y&0xffff);  vv[3]=(u16)(v0v.y>>16);
            vv[4]=(u16)(v0v.z&0xffff);  vv[5]=(u16)(v0v.z>>16);
            vv[6]=(u16)(v0v.w&0xffff);  vv[7]=(u16)(v0v.w>>16);
            vv[8]=(u16)(v1v.x&0xffff);  vv[9]=(u16)(v1v.x>>16);
            vv[10]=(u16)(v1v.y&0xffff); vv[11]=(u16)(v1v.y>>16);
            vv[12]=(u16)(v1v.z&0xffff); vv[13]=(u16)(v1v.z>>16);
            vv[14]=(u16)(v1v.w&0xffff); vv[15]=(u16)(v1v.w>>16);
#pragma unroll
            for (int j = 0; j < 16; ++j) vT_s[skof + j][srow] = vv[j];
        }
        float sq = sqr8bf(k0v) + sqr8bf(k1v);
        sq += __shfl_xor(sq, 1);
        sq += __shfl_xor(sq, 2);
        if ((tid & 3) == 0) nrm_s[srow] = (ncur < NTOK) ? 0.5f * sq : 1e30f;
        __syncthreads();

        // prefetch next tile under the MFMA work
        if (t < 3) {
            const int n = (t + 1) * 64 + srow;
            k0v = (uint4){0,0,0,0}; k1v = (uint4){0,0,0,0};
            v0v = (uint4){0,0,0,0}; v1v = (uint4){0,0,0,0};
            if (n < NTOK) {
                const u16* kp = qkv + ((size_t)(b * NTOK + n)) * 576 + 192 + h * 64 + skof;
                k0v = *(const uint4*)kp; k1v = *(const uint4*)(kp + 8);
                v0v = *(const uint4*)(kp + 192); v1v = *(const uint4*)(kp + 200);
            }
        }

        // pk tile: C[n 64][f 64-per-wave] = k @ pm^T
        floatx4 pa[4][4];
#pragma unroll
        for (int i = 0; i < 4; ++i)
#pragma unroll
            for (int j = 0; j < 4; ++j) pa[i][j] = (floatx4){0.f,0.f,0.f,0.f};
#pragma unroll
        for (int ks = 0; ks < 2; ++ks) {
            short8 a[4], bb[4];
#pragma unroll
            for (int rf = 0; rf < 4; ++rf)
                a[rf] = *(const short8*)&kt_s[rf*16 + l16][ks*32 + quad*8];
#pragma unroll
            for (int cf = 0; cf < 4; ++cf)
                bb[cf] = *(const short8*)&pm_s[fbase + cf*16 + l16][ks*32 + quad*8];
#pragma unroll
            for (int rf = 0; rf < 4; ++rf)
#pragma unroll
                for (int cf = 0; cf < 4; ++cf)
                    pa[rf][cf] = __builtin_amdgcn_mfma_f32_16x16x32_bf16(a[rf], bb[cf], pa[rf][cf], 0, 0, 0);
        }

        // exp epilogue: write transposed [f][n] into LDS (packed b32), ksum partials
        float ksp[4] = {0.f, 0.f, 0.f, 0.f};
#pragma unroll
        for (int rf = 0; rf < 4; ++rf) {
            const int nl = rf * 16 + quad * 4;
            const float nr0 = nrm_s[nl + 0], nr1 = nrm_s[nl + 1];
            const float nr2 = nrm_s[nl + 2], nr3 = nrm_s[nl + 3];
#pragma unroll
            for (int cf = 0; cf < 4; ++cf) {
                const int f = fbase + cf * 16 + l16;
                const u16 b0 = f2bf(__expf(pa[rf][cf][0] - nr0) * scale);
                const u16 b1 = f2bf(__expf(pa[rf][cf][1] - nr1) * scale);
                const u16 b2 = f2bf(__expf(pa[rf][cf][2] - nr2) * scale);
                const u16 b3 = f2bf(__expf(pa[rf][cf][3] - nr3) * scale);
                ksp[cf] += bf2f(b0) + bf2f(b1) + bf2f(b2) + bf2f(b3);
                *(u32*)&pkT_s[f][nl]     = (u32)b0 | ((u32)b1 << 16);
                *(u32*)&pkT_s[f][nl + 2] = (u32)b2 | ((u32)b3 << 16);
            }
        }
#pragma unroll
        for (int cf = 0; cf < 4; ++cf) {
            float v = ksp[cf];
            v += __shfl_xor(v, 16);
            v += __shfl_xor(v, 32);
            if (quad == 0) ksum_s[fbase + cf*16 + l16] += v;
        }

        // kv accumulate: C[d 64][f 64-per-wave] += vT @ pkT^T
        // (each wave reads only the pkT rows it wrote -> no barrier needed)
#pragma unroll
        for (int ks = 0; ks < 2; ++ks) {
            short8 a[4], bb[4];
#pragma unroll
            for (int rf = 0; rf < 4; ++rf)
                a[rf] = *(const short8*)&vT_s[rf*16 + l16][ks*32 + quad*8];
#pragma unroll
            for (int cf = 0; cf < 4; ++cf)
                bb[cf] = *(const short8*)&pkT_s[fbase + cf*16 + l16][ks*32 + quad*8];
#pragma unroll
            for (int rf = 0; rf < 4; ++rf)
#pragma unroll
                for (int cf = 0; cf < 4; ++cf)
                    kv[rf][cf] = __builtin_amdgcn_mfma_f32_16x16x32_bf16(a[rf], bb[cf], kv[rf][cf], 0, 0, 0);
        }
    }

    __syncthreads();
    ksum[(size_t)bh * 256 + tid] = ksum_s[tid];
#pragma unroll
    for (int rf = 0; rf < 4; ++rf)
#pragma unroll
        for (int cf = 0; cf < 4; ++cf) {
            const int f = fbase + cf * 16 + l16;
#pragma unroll
            for (int reg = 0; reg < 4; ++reg) {
                const int d = rf * 16 + quad * 4 + reg;
                kvT[((size_t)bh * 64 + d) * 256 + f] = f2bf(kv[rf][cf][reg]);
            }
        }
}

// ================= fused performer attention, stage 2 =====================
// Per (b,h, 64-token q-tile): pq = exp(q.pm^T - nrm)*s (LDS-resident),
// den = pq . ksum, out[n][d] = (pq . kvT[d]) / den -> ATNB directly.
__global__ __launch_bounds__(256) void attn_out(
    const u16* __restrict__ qkv, const u16* __restrict__ pmb,
    const u16* __restrict__ kvT, const float* __restrict__ ksum,
    u16* __restrict__ attn_o)
{
    __shared__ u16 pm_s[256][72];     // [f][d]
    __shared__ u16 q_s[64][72];       // [n][d]
    __shared__ u16 pq_s[64][264];     // [n][f]
    __shared__ u16 kv_s[64][264];     // [d][f]
    __shared__ float nrm_s[64];
    __shared__ float den_s[4][64];

    const int tid = threadIdx.x;
    const int lane = tid & 63, wave = tid >> 6;
    const int l16 = lane & 15, quad = lane >> 4;
    const int bh = blockIdx.y, b = bh / NH, h = bh % NH;
    const int n0 = blockIdx.x * 64;
    const int fbase = wave * 64;
    const int srow = tid >> 2, skof = (tid & 3) * 16;
    const float scale = 0.35355339059327373f;

#pragma unroll
    for (int j = 0; j < 8; ++j) {
        const int flat = j * 256 + tid;
        const int f = flat >> 3, o = (flat & 7) * 8;
        *(uint4*)&pm_s[f][o] = *(const uint4*)(pmb + f * 64 + o);
    }
#pragma unroll
    for (int j = 0; j < 8; ++j) {
        const int flat = j * 256 + tid;
        const int d = flat >> 5, o = (flat & 31) * 8;
        *(uint4*)&kv_s[d][o] = *(const uint4*)(kvT + ((size_t)bh * 64 + d) * 256 + o);
    }
    {
        const int n = n0 + srow;
        uint4 q0 = {0,0,0,0}, q1 = {0,0,0,0};
        if (n < NTOK) {
            const u16* qp = qkv + ((size_t)(b * NTOK + n)) * 576 + h * 64 + skof;
            q0 = *(const uint4*)qp; q1 = *(const uint4*)(qp + 8);
        }
        *(uint4*)&q_s[srow][skof]     = q0;
        *(uint4*)&q_s[srow][skof + 8] = q1;
        float sq = sqr8bf(q0) + sqr8bf(q1);
        sq += __shfl_xor(sq, 1);
        sq += __shfl_xor(sq, 2);
        if ((tid & 3) == 0) nrm_s[srow] = (n < NTOK) ? 0.5f * sq : 1e30f;
    }
    float ksr[4];
#pragma unroll
    for (int cf = 0; cf < 4; ++cf)
        ksr[cf] = ksum[(size_t)bh * 256 + fbase + cf * 16 + l16];
    __syncthreads();

    // pq tile: C[n 64][f 64-per-wave] = q @ pm^T
    floatx4 pa[4][4];
#pragma unroll
    for (int i = 0; i < 4; ++i)
#pragma unroll
        for (int j = 0; j < 4; ++j) pa[i][j] = (floatx4){0.f,0.f,0.f,0.f};
#pragma unroll
    for (int ks = 0; ks < 2; ++ks) {
        short8 a[4], bb[4];
#pragma unroll
        for (int rf = 0; rf < 4; ++rf)
            a[rf] = *(const short8*)&q_s[rf*16 + l16][ks*32 + quad*8];
#pragma unroll
        for (int cf = 0; cf < 4; ++cf)
            bb[cf] = *(const short8*)&pm_s[fbase + cf*16 + l16][ks*32 + quad*8];
#pragma unroll
        for (int rf = 0; rf < 4; ++rf)
#pragma unroll
            for (int cf = 0; cf < 4; ++cf)
                pa[rf][cf] = __builtin_amdgcn_mfma_f32_16x16x32_bf16(a[rf], bb[cf], pa[rf][cf], 0, 0, 0);
    }

    // exp epilogue -> pq_s [n][f]; den partials from bf16-rounded pq
    float dpart[16];
#pragma unroll
    for (int i = 0; i < 16; ++i) dpart[i] = 0.f;
#pragma unroll
    for (int rf = 0; rf < 4; ++rf) {
        const int nl = rf * 16 + quad * 4;
        const float nr0 = nrm_s[nl + 0], nr1 = nrm_s[nl + 1];
        const float nr2 = nrm_s[nl + 2], nr3 = nrm_s[nl + 3];
#pragma unroll
        for (int cf = 0; cf < 4; ++cf) {
            const int f = fbase + cf * 16 + l16;
            const u16 b0 = f2bf(__expf(pa[rf][cf][0] - nr0) * scale);
            const u16 b1 = f2bf(__expf(pa[rf][cf][1] - nr1) * scale);
            const u16 b2 = f2bf(__expf(pa[rf][cf][2] - nr2) * scale);
            const u16 b3 = f2bf(__expf(pa[rf][cf][3] - nr3) * scale);
            pq_s[nl + 0][f] = b0;
            pq_s[nl + 1][f] = b1;
            pq_s[nl + 2][f] = b2;
            pq_s[nl + 3][f] = b3;
            dpart[rf*4 + 0] += bf2f(b0) * ksr[cf];
            dpart[rf*4 + 1] += bf2f(b1) * ksr[cf];
            dpart[rf*4 + 2] += bf2f(b2) * ksr[cf];
            dpart[rf*4 + 3] += bf2f(b3) * ksr[cf];
        }
    }
#pragma unroll
    for (int i = 0; i < 16; ++i) {
        float d = dpart[i];
        d += __shfl_xor(d, 1); d += __shfl_xor(d, 2);
        d += __shfl_xor(d, 4); d += __shfl_xor(d, 8);
        dpart[i] = d;
    }
    if (l16 == 0) {
#pragma unroll
        for (int rf = 0; rf < 4; ++rf)
#pragma unroll
            for (int reg = 0; reg < 4; ++reg)
                den_s[wave][rf*16 + quad*4 + reg] = dpart[rf*4 + reg];
    }
    __syncthreads();

    // out: C[n 64][d 64], waves 2x2, K = 256
    const int wr = wave & 1, wc = wave >> 1;
    floatx4 oc[2][2];
#pragma unroll
    for (int i = 0; i < 2; ++i)
#pragma unroll
        for (int j = 0; j < 2; ++j) oc[i][j] = (floatx4){0.f,0.f,0.f,0.f};
#pragma unroll
    for (int ks = 0; ks < 8; ++ks) {
        short8 a[2], bb[2];
#pragma unroll
        for (int rf = 0; rf < 2; ++rf)
            a[rf] = *(const short8*)&pq_s[wr*32 + rf*16 + l16][ks*32 + quad*8];
#pragma unroll
        for (int cf = 0; cf < 2; ++cf)
            bb[cf] = *(const short8*)&kv_s[wc*32 + cf*16 + l16][ks*32 + quad*8];
#pragma unroll
        for (int rf = 0; rf < 2; ++rf)
#pragma unroll
            for (int cf = 0; cf < 2; ++cf)
                oc[rf][cf] = __builtin_amdgcn_mfma_f32_16x16x32_bf16(a[rf], bb[cf], oc[rf][cf], 0, 0, 0);
    }

#pragma unroll
    for (int rf = 0; rf < 2; ++rf) {
#pragma unroll
        for (int reg = 0; reg < 4; ++reg) {
            const int nl = wr*32 + rf*16 + quad*4 + reg;
            const int gn = n0 + nl;
            if (gn >= NTOK) continue;
            const float di = 1.f / (den_s[0][nl] + den_s[1][nl] + den_s[2][nl] + den_s[3][nl]);
#pragma unroll
            for (int cf = 0; cf < 2; ++cf) {
                const int d = wc*32 + cf*16 + l16;
                attn_o[((size_t)(b * NTOK + gn)) * EMB + h * 64 + d] =
                    f2bf(oc[rf][cf][reg] * di);
            }
        }
    }
}

// ---------------- im2col (bf16 out) ----------------
__global__ void im2col_kernel(const float* __restrict__ x, u16* __restrict__ p, int total)
{
    const int i = blockIdx.x * 256 + threadIdx.x;
    if (i >= total) return;
    const int col = i % 768, row = i / 768;
    const int px = col & 15, py = (col >> 4) & 15, c = col >> 8;
    const int gx = row % 14, gy = (row / 14) % 14, b = row / 196;
    p[i] = f2bf(x[((size_t)(b * 3 + c) * 224 + gy * 16 + py) * 224 + gx * 16 + px]);
}

// ---------------- patch-embed finish ----------------
__global__ void embed_finish(const float* __restrict__ tok, const float* __restrict__ cls,
                             const float* __restrict__ pos, const float* __restrict__ w,
                             const float* __restrict__ b, float* __restrict__ h)
{
    const int wid = threadIdx.x >> 6, lane = threadIdx.x & 63;
    const int r = blockIdx.x * 4 + wid;
    if (r >= MTOT) return;
    const int bb = r / NTOK, t = r % NTOK;
    float* q = h + (size_t)r * EMB;
    if (t == 0) {
        q[lane]       = cls[lane]       + pos[lane];
        q[lane + 64]  = cls[lane + 64]  + pos[lane + 64];
        q[lane + 128] = cls[lane + 128] + pos[lane + 128];
        return;
    }
    const float* p = tok + ((size_t)bb * NPATCH + (t - 1)) * EMB;
    float x0 = p[lane], x1 = p[lane + 64], x2 = p[lane + 128];
    float s = x0 + x1 + x2;
#pragma unroll
    for (int off = 32; off; off >>= 1) s += __shfl_xor(s, off);
    const float mu = s * (1.f / 192.f);
    const float d0 = x0 - mu, d1 = x1 - mu, d2 = x2 - mu;
    float v = d0 * d0 + d1 * d1 + d2 * d2;
#pragma unroll
    for (int off = 32; off; off >>= 1) v += __shfl_xor(v, off);
    const float rstd = rsqrtf(v * (1.f / 192.f) + 1e-5f);
    const float* pr = pos + (size_t)t * EMB;
    q[lane]       = d0 * rstd * w[lane]       + b[lane]       + pr[lane];
    q[lane + 64]  = d1 * rstd * w[lane + 64]  + b[lane + 64]  + pr[lane + 64];
    q[lane + 128] = d2 * rstd * w[lane + 128] + b[lane + 128] + pr[lane + 128];
}

// ---------------- LayerNorm over 192; bf16 or fp32 out ----------------
__global__ void ln192(const float* __restrict__ in, int in_stride,
                      const float* __restrict__ w, const float* __restrict__ b,
                      u16* __restrict__ outb, float* __restrict__ outf, int rows)
{
    const int wid = threadIdx.x >> 6, lane = threadIdx.x & 63;
    const int r = blockIdx.x * 4 + wid;
    if (r >= rows) return;
    const float* p = in + (size_t)r * in_stride;
    float x0 = p[lane], x1 = p[lane + 64], x2 = p[lane + 128];
    float s = x0 + x1 + x2;
#pragma unroll
    for (int off = 32; off; off >>= 1) s += __shfl_xor(s, off);
    const float mu = s * (1.f / 192.f);
    const float d0 = x0 - mu, d1 = x1 - mu, d2 = x2 - mu;
    float v = d0 * d0 + d1 * d1 + d2 * d2;
#pragma unroll
    for (int off = 32; off; off >>= 1) v += __shfl_xor(v, off);
    const float rstd = rsqrtf(v * (1.f / 192.f) + 1e-5f);
    const float y0 = d0 * rstd * w[lane]       + b[lane];
    const float y1 = d1 * rstd * w[lane + 64]  + b[lane + 64];
    const float y2 = d2 * rstd * w[lane + 128] + b[lane + 128];
    if (outf) {
        float* q = outf + (size_t)r * EMB;
        q[lane] = y0; q[lane + 64] = y1; q[lane + 128] = y2;
    } else {
        u16* q = outb + (size_t)r * EMB;
        q[lane] = f2bf(y0); q[lane + 64] = f2bf(y1); q[lane + 128] = f2bf(y2);
    }
}

// ---------------- fp32 GEMM (head / exits only) ----------------
__global__ __launch_bounds__(256) void gemm_f32(
    const float* __restrict__ A, const float* __restrict__ Bm,
    const float* __restrict__ bias, float* __restrict__ C,
    int M, int N, int K)
{
    __shared__ float As[16][68];
    __shared__ float Bs[16][64];
    const int tid = threadIdx.x;
    const int tx = tid & 15, ty = tid >> 4;
    const int m0 = blockIdx.y * 64, n0 = blockIdx.x * 64;
    float acc[4][4] = {};

    for (int k0 = 0; k0 < K; k0 += 16) {
        {
            const int c = tid & 15, r4 = tid >> 4;
#pragma unroll
            for (int i = 0; i < 4; ++i) {
                const int r = r4 + i * 16, gm = m0 + r;
                As[c][r] = (gm < M) ? A[(size_t)gm * K + (k0 + c)] : 0.f;
            }
        }
        {
            const int cb = tid & 63, rb4 = tid >> 6;
#pragma unroll
            for (int i = 0; i < 4; ++i) {
                const int rb = rb4 + i * 4;
                const int gn = n0 + cb;
                Bs[rb][cb] = (gn < N) ? Bm[(size_t)(k0 + rb) * N + gn] : 0.f;
            }
        }
        __syncthreads();
#pragma unroll
        for (int kk = 0; kk < 16; ++kk) {
            const float4 av = *reinterpret_cast<const float4*>(&As[kk][ty * 4]);
            const float4 bv = *reinterpret_cast<const float4*>(&Bs[kk][tx * 4]);
            const float a_[4] = {av.x, av.y, av.z, av.w};
            const float b_[4] = {bv.x, bv.y, bv.z, bv.w};
#pragma unroll
            for (int i2 = 0; i2 < 4; ++i2)
#pragma unroll
                for (int j2 = 0; j2 < 4; ++j2)
                    acc[i2][j2] = fmaf(a_[i2], b_[j2], acc[i2][j2]);
        }
        __syncthreads();
    }

#pragma unroll
    for (int i = 0; i < 4; ++i) {
        const int gm = m0 + ty * 4 + i;
        if (gm >= M) continue;
#pragma unroll
        for (int j = 0; j < 4; ++j) {
            const int gn = n0 + tx * 4 + j;
            if (gn >= N) continue;
            C[(size_t)gm * N + gn] = acc[i][j] + bias[gn];
        }
    }
}

// ---------------- mean over tokens for exits ----------------
__global__ void pool_kernel(const float* __restrict__ h, float* __restrict__ pooled)
{
    const int b = blockIdx.x, e = threadIdx.x;  // block 192
    float s = 0.f;
    for (int n = 0; n < NTOK; ++n) s += h[((size_t)(b * NTOK + n)) * EMB + e];
    pooled[b * EMB + e] = s * (1.f / 197.f);
}

// ---------------- host launch ----------------
extern "C" void kernel_launch(void* const* d_in, const int* in_sizes, int n_in,
                              void* d_out, int out_size, void* d_ws, size_t ws_size,
                              hipStream_t stream)
{
    const float* x          = (const float*)d_in[0];
    const float* patch_w    = (const float*)d_in[1];
    const float* patch_b    = (const float*)d_in[2];
    const float* pe_norm_w  = (const float*)d_in[3];
    const float* pe_norm_b  = (const float*)d_in[4];
    const float* cls_token  = (const float*)d_in[5];
    const float* pos_embed  = (const float*)d_in[6];
    const float* norm1_w    = (const float*)d_in[7];
    const float* norm1_b    = (const float*)d_in[8];
    const float* qkv_w      = (const float*)d_in[9];
    const float* qkv_b      = (const float*)d_in[10];
    const float* proj_mat   = (const float*)d_in[11];
    const float* attn_pw    = (const float*)d_in[12];
    const float* attn_pb    = (const float*)d_in[13];
    const float* norm2_w    = (const float*)d_in[14];
    const float* norm2_b    = (const float*)d_in[15];
    const float* fc1_w      = (const float*)d_in[16];
    const float* fc1_b      = (const float*)d_in[17];
    const float* fc2_w      = (const float*)d_in[18];
    const float* fc2_b      = (const float*)d_in[19];
    const float* exit_w     = (const float*)d_in[20];
    const float* exit_b     = (const float*)d_in[21];
    const float* fnorm_w    = (const float*)d_in[22];
    const float* fnorm_b    = (const float*)d_in[23];
    const float* head_w     = (const float*)d_in[24];
    const float* head_b     = (const float*)d_in[25];
    float* out = (float*)d_out;

    float* ws = (float*)d_ws;
    // workspace layout (float-slot offsets) — PQb/PKT/VT regions now unused
    float* H     = ws + 0;                  // 12608*192 fp32       -> 2,420,736
    u16*   QKVB  = (u16*)(ws + 2420736);    // 12608*576 bf16 (3,631,104 fl)
    u16*   XLNB  = (u16*)(ws + 6051840);    // 12608*192 bf16 (1,210,368 fl)
    u16*   KVT   = (u16*)(ws + 19968000);   // 192*64*256 bf16 (1,572,864 fl)
    u16*   MIDB  = (u16*)(ws + 21540864);   // 12608*768 bf16 (4,841,472 fl)
    u16*   ATNB  = (u16*)(ws + 26382336);   // 12608*192 bf16 (1,210,368 fl)
    float* XLNF  = ws + 27592704;           // 64*192
    float* POOL  = ws + 27604992;           // 64*192
    float* KSUM  = ws + 27617280;           // 192*256
    u16*   QKVWT = (u16*)(ws + 27666432);   // 12*576*192 bf16 (663,552 fl)
    u16*   APWT  = (u16*)(ws + 28329984);   // 12*192*192 bf16 (221,184 fl)
    u16*   F1WT  = (u16*)(ws + 28551168);   // 12*768*192 bf16 (884,736 fl)
    u16*   F2WT  = (u16*)(ws + 29435904);   // 12*192*768 bf16 (884,736 fl)
    u16*   PATWB = (u16*)(ws + 30320640);   // 192*768 bf16 (73,728 fl)
    u16*   PMB   = (u16*)(ws + 30394368);   // 12*256*64 bf16 (98,304 fl)
    // aliases (disjoint lifetimes)
    u16*   P_IMB = MIDB;                    // im2col [12544,768] bf16 (prologue only)
    float* TOK   = (float*)QKVB;            // patch tokens [12544,192] fp32 (prologue only)

    if (ws_size < (size_t)30492672 * sizeof(float)) return;

    // ---- weight prep ----
    cvt_bf16<<<(147456 + 255) / 256, 256, 0, stream>>>(patch_w, PATWB, 147456);
    cvt_bf16<<<(196608 + 255) / 256, 256, 0, stream>>>(proj_mat, PMB, 196608);
    tr_bf16<<<(1327104 + 255) / 256, 256, 0, stream>>>(qkv_w,   QKVWT, 192, 576, 1327104);
    tr_bf16<<<(442368 + 255) / 256, 256, 0, stream>>>(attn_pw, APWT,  192, 192, 442368);
    tr_bf16<<<(1769472 + 255) / 256, 256, 0, stream>>>(fc1_w,   F1WT,  192, 768, 1769472);
    tr_bf16<<<(1769472 + 255) / 256, 256, 0, stream>>>(fc2_w,   F2WT,  768, 192, 1769472);

    // ---- patch embed ----
    im2col_kernel<<<(MPAT * 768 + 255) / 256, 256, 0, stream>>>(x, P_IMB, MPAT * 768);
    gemm_bf16<<<dim3(3, 196), 256, 0, stream>>>(P_IMB, PATWB, patch_b, nullptr,
                                                TOK, nullptr, MPAT, EMB, 768, 0);
    embed_finish<<<(MTOT + 3) / 4, 256, 0, stream>>>(TOK, cls_token, pos_embed,
                                                     pe_norm_w, pe_norm_b, H);
    // LN1 of layer 0
    ln192<<<(MTOT + 3) / 4, 256, 0, stream>>>(H, EMB, norm1_w, norm1_b,
                                              XLNB, nullptr, MTOT);

    // ---- transformer layers ----
    for (int i = 0; i < 12; ++i) {
        const u16* qwt  = QKVWT + (size_t)i * 576 * 192;
        const u16* pwt  = APWT  + (size_t)i * 192 * 192;
        const u16* f1wt = F1WT  + (size_t)i * 768 * 192;
        const u16* f2wt = F2WT  + (size_t)i * 192 * 768;
        const u16* pmb  = PMB   + (size_t)i * 256 * 64;
        const float* qb  = qkv_b   + (size_t)i * 576;
        const float* pb  = attn_pb + (size_t)i * 192;
        const float* f1b = fc1_b   + (size_t)i * 768;
        const float* f2b = fc2_b   + (size_t)i * 192;

        gemm_bf16<<<dim3(9, 197), 256, 0, stream>>>(XLNB, qwt, qb, nullptr,
                                                    nullptr, QKVB, MTOT, 576, 192, 3);
        attn_pkv<<<dim3(BHT), 256, 0, stream>>>(QKVB, pmb, KVT, KSUM);
        attn_out<<<dim3(4, BHT), 256, 0, stream>>>(QKVB, pmb, KVT, KSUM, ATNB);
        gemm_bf16<<<dim3(3, 197), 256, 0, stream>>>(ATNB, pwt, pb, H,
                                                    H, nullptr, MTOT, EMB, EMB, 1);
        ln192<<<(MTOT + 3) / 4, 256, 0, stream>>>(H, EMB, norm2_w + i * EMB,
                                                  norm2_b + i * EMB, XLNB, nullptr, MTOT);
        gemm_bf16<<<dim3(12, 197), 256, 0, stream>>>(XLNB, f1wt, f1b, nullptr,
                                                     nullptr, MIDB, MTOT, MLPD, 192, 2);
        gemm_bf16<<<dim3(3, 197), 256, 0, stream>>>(MIDB, f2wt, f2b, H,
                                                    H, nullptr, MTOT, EMB, MLPD, 1);

        const int e = (i == 3) ? 0 : (i == 7) ? 1 : (i == 11) ? 2 : -1;
        if (e >= 0) {
            pool_kernel<<<BB, 192, 0, stream>>>(H, POOL);
            gemm_f32<<<dim3(16, 1), 256, 0, stream>>>(POOL, exit_w + (size_t)e * 192 * 1000,
                                                      exit_b + (size_t)e * 1000,
                                                      out + (size_t)(1 + e) * BB * NCLS,
                                                      BB, NCLS, EMB);
        }
        if (i < 11) {
            ln192<<<(MTOT + 3) / 4, 256, 0, stream>>>(H, EMB, norm1_w + (i + 1) * EMB,
                                                      norm1_b + (i + 1) * EMB,
                                                      XLNB, nullptr, MTOT);
        }
    }

    // ---- head ----
    ln192<<<(BB + 3) / 4, 256, 0, stream>>>(H, NTOK * EMB, fnorm_w, fnorm_b,
                                            nullptr, XLNF, BB);
    gemm_f32<<<dim3(16, 1), 256, 0, stream>>>(XLNF, head_w, head_b, out, BB, NCLS, EMB);
}

// Round 2
// 1759.888 us; speedup vs baseline: 1.0376x; 1.0154x over previous
//
#include <hip/hip_runtime.h>
#include <math.h>

typedef unsigned short u16;
typedef unsigned int u32;
typedef __attribute__((ext_vector_type(8))) short short8;
typedef __attribute__((ext_vector_type(4))) float floatx4;

// ---------------- problem constants ----------------
#define BB 64
#define NTOK 197
#define NPATCH 196
#define EMB 192
#define NH 3
#define HD 64
#define FEAT 256
#define MLPD 768
#define NCLS 1000
#define MTOT (BB*NTOK)      // 12608
#define MPAT (BB*NPATCH)    // 12544
#define BHT (BB*NH)         // 192

// ---------------- bf16 helpers ----------------
__device__ __forceinline__ u16 f2bf(float x) {
    u32 u = __builtin_bit_cast(u32, x);
    u32 r = u + 0x7FFFu + ((u >> 16) & 1u);
    return (u16)(r >> 16);
}
__device__ __forceinline__ float bf2f(u16 u) {
    return __builtin_bit_cast(float, (u32)u << 16);
}
__device__ __forceinline__ float sqr8bf(uint4 v) {
    float s = 0.f;
    float t;
    t = bf2f((u16)(v.x & 0xffff)); s += t*t;  t = bf2f((u16)(v.x >> 16)); s += t*t;
    t = bf2f((u16)(v.y & 0xffff)); s += t*t;  t = bf2f((u16)(v.y >> 16)); s += t*t;
    t = bf2f((u16)(v.z & 0xffff)); s += t*t;  t = bf2f((u16)(v.z >> 16)); s += t*t;
    t = bf2f((u16)(v.w & 0xffff)); s += t*t;  t = bf2f((u16)(v.w >> 16)); s += t*t;
    return s;
}

// ---------------- weight prep ----------------
__global__ void cvt_bf16(const float* __restrict__ in, u16* __restrict__ out, int n)
{
    const int i = blockIdx.x * 256 + threadIdx.x;
    if (i < n) out[i] = f2bf(in[i]);
}

// in [L][R][C] fp32 -> out [L][C][R] bf16
__global__ void tr_bf16(const float* __restrict__ in, u16* __restrict__ out,
                        int R, int C, int total)
{
    const int i = blockIdx.x * 256 + threadIdx.x;
    if (i >= total) return;
    const int r = i % R;
    const int c = (i / R) % C;
    const int l = i / (R * C);
    out[i] = f2bf(in[((size_t)l * R + r) * C + c]);
}

// ================= MFMA bf16 GEMM, 128x64 tile =================
// C[M,N] = A[M,K] @ Bt[N,K]^T + bias
// mode 0: fp32 out ; mode 2: gelu -> bf16 out ; mode 3: bf16 out
__global__ __launch_bounds__(256) void gemm_bf16(
    const u16* __restrict__ A, const u16* __restrict__ Bt,
    const float* __restrict__ bias,
    float* __restrict__ Cf, u16* __restrict__ Cb,
    int M, int N, int K, int mode)
{
    __shared__ u16 As[128][72];
    __shared__ u16 Bs[64][72];
    const int tid = threadIdx.x;
    const int lane = tid & 63, wave = tid >> 6;
    const int l16 = lane & 15, quad = lane >> 4;
    const int m0 = blockIdx.y * 128, n0 = blockIdx.x * 64;
    const int arow = tid >> 1, aof = (tid & 1) * 32;   // 32 u16 = 4 uint4 per thread
    const int brow = tid >> 2, bof = (tid & 3) * 16;   // 16 u16 = 2 uint4 per thread

    floatx4 acc[2][4];
#pragma unroll
    for (int i = 0; i < 2; ++i)
#pragma unroll
        for (int j = 0; j < 4; ++j) acc[i][j] = (floatx4){0.f,0.f,0.f,0.f};

    const int gmA = m0 + arow;
    const bool aok = (gmA < M);
    const u16* ap = A + (size_t)gmA * K + aof;
    const u16* bp = Bt + (size_t)(n0 + brow) * K + bof;

    for (int k0 = 0; k0 < K; k0 += 64) {
        uint4 a0 = {0,0,0,0}, a1 = {0,0,0,0}, a2 = {0,0,0,0}, a3 = {0,0,0,0};
        if (aok) {
            a0 = *(const uint4*)(ap + k0);
            a1 = *(const uint4*)(ap + k0 + 8);
            a2 = *(const uint4*)(ap + k0 + 16);
            a3 = *(const uint4*)(ap + k0 + 24);
        }
        const uint4 b0 = *(const uint4*)(bp + k0);
        const uint4 b1 = *(const uint4*)(bp + k0 + 8);
        if (k0) __syncthreads();
        *(uint4*)&As[arow][aof]      = a0;
        *(uint4*)&As[arow][aof + 8]  = a1;
        *(uint4*)&As[arow][aof + 16] = a2;
        *(uint4*)&As[arow][aof + 24] = a3;
        *(uint4*)&Bs[brow][bof]      = b0;
        *(uint4*)&Bs[brow][bof + 8]  = b1;
        __syncthreads();
#pragma unroll
        for (int ks = 0; ks < 2; ++ks) {
            short8 af[2], bf[4];
#pragma unroll
            for (int rf = 0; rf < 2; ++rf)
                af[rf] = *(const short8*)&As[wave*32 + rf*16 + l16][ks*32 + quad*8];
#pragma unroll
            for (int cf = 0; cf < 4; ++cf)
                bf[cf] = *(const short8*)&Bs[cf*16 + l16][ks*32 + quad*8];
#pragma unroll
            for (int rf = 0; rf < 2; ++rf)
#pragma unroll
                for (int cf = 0; cf < 4; ++cf)
                    acc[rf][cf] = __builtin_amdgcn_mfma_f32_16x16x32_bf16(af[rf], bf[cf], acc[rf][cf], 0, 0, 0);
        }
    }

    const int rbase = m0 + wave * 32 + quad * 4;
    const int cbase = n0 + l16;
#pragma unroll
    for (int rf = 0; rf < 2; ++rf) {
#pragma unroll
        for (int reg = 0; reg < 4; ++reg) {
            const int gm = rbase + rf * 16 + reg;
            if (gm >= M) continue;
#pragma unroll
            for (int cf = 0; cf < 4; ++cf) {
                const int gn = cbase + cf * 16;
                float v = acc[rf][cf][reg] + bias[gn];
                if (mode == 2) {
                    v = 0.5f * v * (1.f + erff(v * 0.70710678118654752f));
                    Cb[(size_t)gm * N + gn] = f2bf(v);
                } else if (mode == 3) {
                    Cb[(size_t)gm * N + gn] = f2bf(v);
                } else {
                    Cf[(size_t)gm * N + gn] = v;
                }
            }
        }
    }
}

// ================= fused GEMM(+bias+residual) + LayerNorm =================
// Tile 64 x 192 (full row), M = 12608 exactly = 197*64.
// H[r][c] += A@Bt^T + bias ; if lnw: XLNB[r][c] = LN_row(H)[c] (bf16)
__global__ __launch_bounds__(256) void gemm_ln(
    const u16* __restrict__ A, const u16* __restrict__ Bt,
    const float* __restrict__ bias,
    const float* __restrict__ lnw, const float* __restrict__ lnb,
    float* __restrict__ H, u16* __restrict__ outb, int K)
{
    __shared__ u16 As[64][72];
    __shared__ u16 Bs[192][72];
    __shared__ float red_s[2][64][2];
    const int tid = threadIdx.x;
    const int lane = tid & 63, wave = tid >> 6;
    const int wr = wave & 1, wc = wave >> 1;
    const int l16 = lane & 15, quad = lane >> 4;
    const int m0 = blockIdx.x * 64;
    const int srow = tid >> 2, skof = (tid & 3) * 16;

    floatx4 acc[2][6];
#pragma unroll
    for (int i = 0; i < 2; ++i)
#pragma unroll
        for (int j = 0; j < 6; ++j) acc[i][j] = (floatx4){0.f,0.f,0.f,0.f};

    const u16* ap = A + (size_t)(m0 + srow) * K + skof;
    const u16* bp = Bt + (size_t)srow * K + skof;
    const size_t bstep = (size_t)64 * K;

    for (int k0 = 0; k0 < K; k0 += 64) {
        const uint4 a0 = *(const uint4*)(ap + k0);
        const uint4 a1 = *(const uint4*)(ap + k0 + 8);
        const uint4 b0 = *(const uint4*)(bp + k0);
        const uint4 b1 = *(const uint4*)(bp + k0 + 8);
        const uint4 b2 = *(const uint4*)(bp + bstep + k0);
        const uint4 b3 = *(const uint4*)(bp + bstep + k0 + 8);
        const uint4 b4 = *(const uint4*)(bp + 2*bstep + k0);
        const uint4 b5 = *(const uint4*)(bp + 2*bstep + k0 + 8);
        if (k0) __syncthreads();
        *(uint4*)&As[srow][skof]           = a0;
        *(uint4*)&As[srow][skof + 8]       = a1;
        *(uint4*)&Bs[srow][skof]           = b0;
        *(uint4*)&Bs[srow][skof + 8]       = b1;
        *(uint4*)&Bs[srow + 64][skof]      = b2;
        *(uint4*)&Bs[srow + 64][skof + 8]  = b3;
        *(uint4*)&Bs[srow + 128][skof]     = b4;
        *(uint4*)&Bs[srow + 128][skof + 8] = b5;
        __syncthreads();
#pragma unroll
        for (int ks = 0; ks < 2; ++ks) {
            short8 af[2], bf[6];
#pragma unroll
            for (int rf = 0; rf < 2; ++rf)
                af[rf] = *(const short8*)&As[wr*32 + rf*16 + l16][ks*32 + quad*8];
#pragma unroll
            for (int cf = 0; cf < 6; ++cf)
                bf[cf] = *(const short8*)&Bs[wc*96 + cf*16 + l16][ks*32 + quad*8];
#pragma unroll
            for (int rf = 0; rf < 2; ++rf)
#pragma unroll
                for (int cf = 0; cf < 6; ++cf)
                    acc[rf][cf] = __builtin_amdgcn_mfma_f32_16x16x32_bf16(af[rf], bf[cf], acc[rf][cf], 0, 0, 0);
        }
    }

    // epilogue: bias + residual -> H (fp32), accumulate row sum / sumsq
    float s_[2][4], q_[2][4];
#pragma unroll
    for (int rf = 0; rf < 2; ++rf)
#pragma unroll
        for (int reg = 0; reg < 4; ++reg) { s_[rf][reg] = 0.f; q_[rf][reg] = 0.f; }

#pragma unroll
    for (int rf = 0; rf < 2; ++rf) {
#pragma unroll
        for (int cf = 0; cf < 6; ++cf) {
            const int gn = wc * 96 + cf * 16 + l16;
            const float bia = bias[gn];
#pragma unroll
            for (int reg = 0; reg < 4; ++reg) {
                const int gm = m0 + wr * 32 + rf * 16 + quad * 4 + reg;
                float v = acc[rf][cf][reg] + bia + H[(size_t)gm * EMB + gn];
                H[(size_t)gm * EMB + gn] = v;
                acc[rf][cf][reg] = v;
                s_[rf][reg] += v;
                q_[rf][reg] += v * v;
            }
        }
    }

    if (lnw) {
#pragma unroll
        for (int rf = 0; rf < 2; ++rf)
#pragma unroll
            for (int reg = 0; reg < 4; ++reg) {
                float s = s_[rf][reg], q = q_[rf][reg];
                s += __shfl_xor(s, 1); q += __shfl_xor(q, 1);
                s += __shfl_xor(s, 2); q += __shfl_xor(q, 2);
                s += __shfl_xor(s, 4); q += __shfl_xor(q, 4);
                s += __shfl_xor(s, 8); q += __shfl_xor(q, 8);
                if (l16 == 0) {
                    const int rl = wr * 32 + rf * 16 + quad * 4 + reg;
                    red_s[wc][rl][0] = s;
                    red_s[wc][rl][1] = q;
                }
            }
        __syncthreads();
#pragma unroll
        for (int rf = 0; rf < 2; ++rf) {
#pragma unroll
            for (int reg = 0; reg < 4; ++reg) {
                const int rl = wr * 32 + rf * 16 + quad * 4 + reg;
                const float ts = red_s[0][rl][0] + red_s[1][rl][0];
                const float tq = red_s[0][rl][1] + red_s[1][rl][1];
                const float mu = ts * (1.f / 192.f);
                const float var = tq * (1.f / 192.f) - mu * mu;
                const float rstd = rsqrtf(fmaxf(var, 0.f) + 1e-5f);
                const int gm = m0 + rl;
#pragma unroll
                for (int cf = 0; cf < 6; ++cf) {
                    const int gn = wc * 96 + cf * 16 + l16;
                    const float y = (acc[rf][cf][reg] - mu) * rstd * lnw[gn] + lnb[gn];
                    outb[(size_t)gm * EMB + gn] = f2bf(y);
                }
            }
        }
    }
}

// ================= fused performer attention, stage 1 =====================
__global__ __launch_bounds__(256) void attn_pkv(
    const u16* __restrict__ qkv, const u16* __restrict__ pmb,
    u16* __restrict__ kvT, float* __restrict__ ksum)
{
    __shared__ u16 pm_s[256][72];     // [f][d]
    __shared__ u16 kt_s[64][72];      // [n][d] tile
    __shared__ u16 vT_s[64][72];      // [d][n] tile
    __shared__ u16 pkT_s[256][72];    // [f][n] tile
    __shared__ float nrm_s[64];
    __shared__ float ksum_s[256];

    const int tid = threadIdx.x;
    const int lane = tid & 63, wave = tid >> 6;
    const int l16 = lane & 15, quad = lane >> 4;
    const int bh = blockIdx.x, b = bh / NH, h = bh % NH;
    const int fbase = wave * 64;
    const int srow = tid >> 2, skof = (tid & 3) * 16;
    const float scale = 0.35355339059327373f;

#pragma unroll
    for (int j = 0; j < 8; ++j) {
        const int flat = j * 256 + tid;
        const int f = flat >> 3, o = (flat & 7) * 8;
        *(uint4*)&pm_s[f][o] = *(const uint4*)(pmb + f * 64 + o);
    }
    ksum_s[tid] = 0.f;

    floatx4 kv[4][4];
#pragma unroll
    for (int i = 0; i < 4; ++i)
#pragma unroll
        for (int j = 0; j < 4; ++j) kv[i][j] = (floatx4){0.f,0.f,0.f,0.f};

    uint4 k0v = {0,0,0,0}, k1v = {0,0,0,0}, v0v = {0,0,0,0}, v1v = {0,0,0,0};
    {
        const u16* kp = qkv + ((size_t)(b * NTOK + srow)) * 576 + 192 + h * 64 + skof;
        k0v = *(const uint4*)kp; k1v = *(const uint4*)(kp + 8);
        v0v = *(const uint4*)(kp + 192); v1v = *(const uint4*)(kp + 200);
    }

    for (int t = 0; t < 4; ++t) {
        const int ncur = t * 64 + srow;
        if (t) __syncthreads();
        *(uint4*)&kt_s[srow][skof]     = k0v;
        *(uint4*)&kt_s[srow][skof + 8] = k1v;
        {
            u16 vv[16];
            vv[0]=(u16)(v0v.x&0xffff);  vv[1]=(u16)(v0v.x>>16);
            vv[2]=(u16)(v0v.y&0xffff);  vv[3]=(u16)(v0v.y>>16);
            vv[4]=(u16)(v0v.z&0xffff);  vv[5]=(u16)(v0v.z>>16);
            vv[6]=(u16)(v0v.w&0xffff);  vv[7]=(u16)(v0v.w>>16);
            vv[8]=(u16)(v1v.x&0xffff);  vv[9]=(u16)(v1v.x>>16);
            vv[10]=(u16)(v1v.y&0xffff); vv[11]=(u16)(v1v.y>>16);
            vv[12]=(u16)(v1v.z&0xffff); vv[13]=(u16)(v1v.z>>16);
            vv[14]=(u16)(v1v.w&0xffff); vv[15]=(u16)(v1v.w>>16);
#pragma unroll
            for (int j = 0; j < 16; ++j) vT_s[skof + j][srow] = vv[j];
        }
        float sq = sqr8bf(k0v) + sqr8bf(k1v);
        sq += __shfl_xor(sq, 1);
        sq += __shfl_xor(sq, 2);
        if ((tid & 3) == 0) nrm_s[srow] = (ncur < NTOK) ? 0.5f * sq : 1e30f;
        __syncthreads();

        if (t < 3) {
            const int n = (t + 1) * 64 + srow;
            k0v = (uint4){0,0,0,0}; k1v = (uint4){0,0,0,0};
            v0v = (uint4){0,0,0,0}; v1v = (uint4){0,0,0,0};
            if (n < NTOK) {
                const u16* kp = qkv + ((size_t)(b * NTOK + n)) * 576 + 192 + h * 64 + skof;
                k0v = *(const uint4*)kp; k1v = *(const uint4*)(kp + 8);
                v0v = *(const uint4*)(kp + 192); v1v = *(const uint4*)(kp + 200);
            }
        }

        floatx4 pa[4][4];
#pragma unroll
        for (int i = 0; i < 4; ++i)
#pragma unroll
            for (int j = 0; j < 4; ++j) pa[i][j] = (floatx4){0.f,0.f,0.f,0.f};
#pragma unroll
        for (int ks = 0; ks < 2; ++ks) {
            short8 a[4], bb[4];
#pragma unroll
            for (int rf = 0; rf < 4; ++rf)
                a[rf] = *(const short8*)&kt_s[rf*16 + l16][ks*32 + quad*8];
#pragma unroll
            for (int cf = 0; cf < 4; ++cf)
                bb[cf] = *(const short8*)&pm_s[fbase + cf*16 + l16][ks*32 + quad*8];
#pragma unroll
            for (int rf = 0; rf < 4; ++rf)
#pragma unroll
                for (int cf = 0; cf < 4; ++cf)
                    pa[rf][cf] = __builtin_amdgcn_mfma_f32_16x16x32_bf16(a[rf], bb[cf], pa[rf][cf], 0, 0, 0);
        }

        float ksp[4] = {0.f, 0.f, 0.f, 0.f};
#pragma unroll
        for (int rf = 0; rf < 4; ++rf) {
            const int nl = rf * 16 + quad * 4;
            const float nr0 = nrm_s[nl + 0], nr1 = nrm_s[nl + 1];
            const float nr2 = nrm_s[nl + 2], nr3 = nrm_s[nl + 3];
#pragma unroll
            for (int cf = 0; cf < 4; ++cf) {
                const int f = fbase + cf * 16 + l16;
                const u16 b0 = f2bf(__expf(pa[rf][cf][0] - nr0) * scale);
                const u16 b1 = f2bf(__expf(pa[rf][cf][1] - nr1) * scale);
                const u16 b2 = f2bf(__expf(pa[rf][cf][2] - nr2) * scale);
                const u16 b3 = f2bf(__expf(pa[rf][cf][3] - nr3) * scale);
                ksp[cf] += bf2f(b0) + bf2f(b1) + bf2f(b2) + bf2f(b3);
                *(u32*)&pkT_s[f][nl]     = (u32)b0 | ((u32)b1 << 16);
                *(u32*)&pkT_s[f][nl + 2] = (u32)b2 | ((u32)b3 << 16);
            }
        }
#pragma unroll
        for (int cf = 0; cf < 4; ++cf) {
            float v = ksp[cf];
            v += __shfl_xor(v, 16);
            v += __shfl_xor(v, 32);
            if (quad == 0) ksum_s[fbase + cf*16 + l16] += v;
        }

#pragma unroll
        for (int ks = 0; ks < 2; ++ks) {
            short8 a[4], bb[4];
#pragma unroll
            for (int rf = 0; rf < 4; ++rf)
                a[rf] = *(const short8*)&vT_s[rf*16 + l16][ks*32 + quad*8];
#pragma unroll
            for (int cf = 0; cf < 4; ++cf)
                bb[cf] = *(const short8*)&pkT_s[fbase + cf*16 + l16][ks*32 + quad*8];
#pragma unroll
            for (int rf = 0; rf < 4; ++rf)
#pragma unroll
                for (int cf = 0; cf < 4; ++cf)
                    kv[rf][cf] = __builtin_amdgcn_mfma_f32_16x16x32_bf16(a[rf], bb[cf], kv[rf][cf], 0, 0, 0);
        }
    }

    __syncthreads();
    ksum[(size_t)bh * 256 + tid] = ksum_s[tid];
#pragma unroll
    for (int rf = 0; rf < 4; ++rf)
#pragma unroll
        for (int cf = 0; cf < 4; ++cf) {
            const int f = fbase + cf * 16 + l16;
#pragma unroll
            for (int reg = 0; reg < 4; ++reg) {
                const int d = rf * 16 + quad * 4 + reg;
                kvT[((size_t)bh * 64 + d) * 256 + f] = f2bf(kv[rf][cf][reg]);
            }
        }
}

// ================= fused performer attention, stage 2 =====================
__global__ __launch_bounds__(256) void attn_out(
    const u16* __restrict__ qkv, const u16* __restrict__ pmb,
    const u16* __restrict__ kvT, const float* __restrict__ ksum,
    u16* __restrict__ attn_o)
{
    __shared__ u16 pm_s[256][72];     // [f][d]
    __shared__ u16 q_s[64][72];       // [n][d]
    __shared__ u16 pq_s[64][264];     // [n][f]
    __shared__ u16 kv_s[64][264];     // [d][f]
    __shared__ float nrm_s[64];
    __shared__ float den_s[4][64];

    const int tid = threadIdx.x;
    const int lane = tid & 63, wave = tid >> 6;
    const int l16 = lane & 15, quad = lane >> 4;
    const int bh = blockIdx.y, b = bh / NH, h = bh % NH;
    const int n0 = blockIdx.x * 64;
    const int fbase = wave * 64;
    const int srow = tid >> 2, skof = (tid & 3) * 16;
    const float scale = 0.35355339059327373f;

#pragma unroll
    for (int j = 0; j < 8; ++j) {
        const int flat = j * 256 + tid;
        const int f = flat >> 3, o = (flat & 7) * 8;
        *(uint4*)&pm_s[f][o] = *(const uint4*)(pmb + f * 64 + o);
    }
#pragma unroll
    for (int j = 0; j < 8; ++j) {
        const int flat = j * 256 + tid;
        const int d = flat >> 5, o = (flat & 31) * 8;
        *(uint4*)&kv_s[d][o] = *(const uint4*)(kvT + ((size_t)bh * 64 + d) * 256 + o);
    }
    {
        const int n = n0 + srow;
        uint4 q0 = {0,0,0,0}, q1 = {0,0,0,0};
        if (n < NTOK) {
            const u16* qp = qkv + ((size_t)(b * NTOK + n)) * 576 + h * 64 + skof;
            q0 = *(const uint4*)qp; q1 = *(const uint4*)(qp + 8);
        }
        *(uint4*)&q_s[srow][skof]     = q0;
        *(uint4*)&q_s[srow][skof + 8] = q1;
        float sq = sqr8bf(q0) + sqr8bf(q1);
        sq += __shfl_xor(sq, 1);
        sq += __shfl_xor(sq, 2);
        if ((tid & 3) == 0) nrm_s[srow] = (n < NTOK) ? 0.5f * sq : 1e30f;
    }
    float ksr[4];
#pragma unroll
    for (int cf = 0; cf < 4; ++cf)
        ksr[cf] = ksum[(size_t)bh * 256 + fbase + cf * 16 + l16];
    __syncthreads();

    floatx4 pa[4][4];
#pragma unroll
    for (int i = 0; i < 4; ++i)
#pragma unroll
        for (int j = 0; j < 4; ++j) pa[i][j] = (floatx4){0.f,0.f,0.f,0.f};
#pragma unroll
    for (int ks = 0; ks < 2; ++ks) {
        short8 a[4], bb[4];
#pragma unroll
        for (int rf = 0; rf < 4; ++rf)
            a[rf] = *(const short8*)&q_s[rf*16 + l16][ks*32 + quad*8];
#pragma unroll
        for (int cf = 0; cf < 4; ++cf)
            bb[cf] = *(const short8*)&pm_s[fbase + cf*16 + l16][ks*32 + quad*8];
#pragma unroll
        for (int rf = 0; rf < 4; ++rf)
#pragma unroll
            for (int cf = 0; cf < 4; ++cf)
                pa[rf][cf] = __builtin_amdgcn_mfma_f32_16x16x32_bf16(a[rf], bb[cf], pa[rf][cf], 0, 0, 0);
    }

    float dpart[16];
#pragma unroll
    for (int i = 0; i < 16; ++i) dpart[i] = 0.f;
#pragma unroll
    for (int rf = 0; rf < 4; ++rf) {
        const int nl = rf * 16 + quad * 4;
        const float nr0 = nrm_s[nl + 0], nr1 = nrm_s[nl + 1];
        const float nr2 = nrm_s[nl + 2], nr3 = nrm_s[nl + 3];
#pragma unroll
        for (int cf = 0; cf < 4; ++cf) {
            const int f = fbase + cf * 16 + l16;
            const u16 b0 = f2bf(__expf(pa[rf][cf][0] - nr0) * scale);
            const u16 b1 = f2bf(__expf(pa[rf][cf][1] - nr1) * scale);
            const u16 b2 = f2bf(__expf(pa[rf][cf][2] - nr2) * scale);
            const u16 b3 = f2bf(__expf(pa[rf][cf][3] - nr3) * scale);
            pq_s[nl + 0][f] = b0;
            pq_s[nl + 1][f] = b1;
            pq_s[nl + 2][f] = b2;
            pq_s[nl + 3][f] = b3;
            dpart[rf*4 + 0] += bf2f(b0) * ksr[cf];
            dpart[rf*4 + 1] += bf2f(b1) * ksr[cf];
            dpart[rf*4 + 2] += bf2f(b2) * ksr[cf];
            dpart[rf*4 + 3] += bf2f(b3) * ksr[cf];
        }
    }
#pragma unroll
    for (int i = 0; i < 16; ++i) {
        float d = dpart[i];
        d += __shfl_xor(d, 1); d += __shfl_xor(d, 2);
        d += __shfl_xor(d, 4); d += __shfl_xor(d, 8);
        dpart[i] = d;
    }
    if (l16 == 0) {
#pragma unroll
        for (int rf = 0; rf < 4; ++rf)
#pragma unroll
            for (int reg = 0; reg < 4; ++reg)
                den_s[wave][rf*16 + quad*4 + reg] = dpart[rf*4 + reg];
    }
    __syncthreads();

    const int wr = wave & 1, wc = wave >> 1;
    floatx4 oc[2][2];
#pragma unroll
    for (int i = 0; i < 2; ++i)
#pragma unroll
        for (int j = 0; j < 2; ++j) oc[i][j] = (floatx4){0.f,0.f,0.f,0.f};
#pragma unroll
    for (int ks = 0; ks < 8; ++ks) {
        short8 a[2], bb[2];
#pragma unroll
        for (int rf = 0; rf < 2; ++rf)
            a[rf] = *(const short8*)&pq_s[wr*32 + rf*16 + l16][ks*32 + quad*8];
#pragma unroll
        for (int cf = 0; cf < 2; ++cf)
            bb[cf] = *(const short8*)&kv_s[wc*32 + cf*16 + l16][ks*32 + quad*8];
#pragma unroll
        for (int rf = 0; rf < 2; ++rf)
#pragma unroll
            for (int cf = 0; cf < 2; ++cf)
                oc[rf][cf] = __builtin_amdgcn_mfma_f32_16x16x32_bf16(a[rf], bb[cf], oc[rf][cf], 0, 0, 0);
    }

#pragma unroll
    for (int rf = 0; rf < 2; ++rf) {
#pragma unroll
        for (int reg = 0; reg < 4; ++reg) {
            const int nl = wr*32 + rf*16 + quad*4 + reg;
            const int gn = n0 + nl;
            if (gn >= NTOK) continue;
            const float di = 1.f / (den_s[0][nl] + den_s[1][nl] + den_s[2][nl] + den_s[3][nl]);
#pragma unroll
            for (int cf = 0; cf < 2; ++cf) {
                const int d = wc*32 + cf*16 + l16;
                attn_o[((size_t)(b * NTOK + gn)) * EMB + h * 64 + d] =
                    f2bf(oc[rf][cf][reg] * di);
            }
        }
    }
}

// ---------------- im2col (bf16 out) ----------------
__global__ void im2col_kernel(const float* __restrict__ x, u16* __restrict__ p, int total)
{
    const int i = blockIdx.x * 256 + threadIdx.x;
    if (i >= total) return;
    const int col = i % 768, row = i / 768;
    const int px = col & 15, py = (col >> 4) & 15, c = col >> 8;
    const int gx = row % 14, gy = (row / 14) % 14, b = row / 196;
    p[i] = f2bf(x[((size_t)(b * 3 + c) * 224 + gy * 16 + py) * 224 + gx * 16 + px]);
}

// ---------------- patch-embed finish ----------------
__global__ void embed_finish(const float* __restrict__ tok, const float* __restrict__ cls,
                             const float* __restrict__ pos, const float* __restrict__ w,
                             const float* __restrict__ b, float* __restrict__ h)
{
    const int wid = threadIdx.x >> 6, lane = threadIdx.x & 63;
    const int r = blockIdx.x * 4 + wid;
    if (r >= MTOT) return;
    const int bb = r / NTOK, t = r % NTOK;
    float* q = h + (size_t)r * EMB;
    if (t == 0) {
        q[lane]       = cls[lane]       + pos[lane];
        q[lane + 64]  = cls[lane + 64]  + pos[lane + 64];
        q[lane + 128] = cls[lane + 128] + pos[lane + 128];
        return;
    }
    const float* p = tok + ((size_t)bb * NPATCH + (t - 1)) * EMB;
    float x0 = p[lane], x1 = p[lane + 64], x2 = p[lane + 128];
    float s = x0 + x1 + x2;
#pragma unroll
    for (int off = 32; off; off >>= 1) s += __shfl_xor(s, off);
    const float mu = s * (1.f / 192.f);
    const float d0 = x0 - mu, d1 = x1 - mu, d2 = x2 - mu;
    float v = d0 * d0 + d1 * d1 + d2 * d2;
#pragma unroll
    for (int off = 32; off; off >>= 1) v += __shfl_xor(v, off);
    const float rstd = rsqrtf(v * (1.f / 192.f) + 1e-5f);
    const float* pr = pos + (size_t)t * EMB;
    q[lane]       = d0 * rstd * w[lane]       + b[lane]       + pr[lane];
    q[lane + 64]  = d1 * rstd * w[lane + 64]  + b[lane + 64]  + pr[lane + 64];
    q[lane + 128] = d2 * rstd * w[lane + 128] + b[lane + 128] + pr[lane + 128];
}

// ---------------- LayerNorm over 192; bf16 or fp32 out ----------------
__global__ void ln192(const float* __restrict__ in, int in_stride,
                      const float* __restrict__ w, const float* __restrict__ b,
                      u16* __restrict__ outb, float* __restrict__ outf, int rows)
{
    const int wid = threadIdx.x >> 6, lane = threadIdx.x & 63;
    const int r = blockIdx.x * 4 + wid;
    if (r >= rows) return;
    const float* p = in + (size_t)r * in_stride;
    float x0 = p[lane], x1 = p[lane + 64], x2 = p[lane + 128];
    float s = x0 + x1 + x2;
#pragma unroll
    for (int off = 32; off; off >>= 1) s += __shfl_xor(s, off);
    const float mu = s * (1.f / 192.f);
    const float d0 = x0 - mu, d1 = x1 - mu, d2 = x2 - mu;
    float v = d0 * d0 + d1 * d1 + d2 * d2;
#pragma unroll
    for (int off = 32; off; off >>= 1) v += __shfl_xor(v, off);
    const float rstd = rsqrtf(v * (1.f / 192.f) + 1e-5f);
    const float y0 = d0 * rstd * w[lane]       + b[lane];
    const float y1 = d1 * rstd * w[lane + 64]  + b[lane + 64];
    const float y2 = d2 * rstd * w[lane + 128] + b[lane + 128];
    if (outf) {
        float* q = outf + (size_t)r * EMB;
        q[lane] = y0; q[lane + 64] = y1; q[lane + 128] = y2;
    } else {
        u16* q = outb + (size_t)r * EMB;
        q[lane] = f2bf(y0); q[lane + 64] = f2bf(y1); q[lane + 128] = f2bf(y2);
    }
}

// ---------------- fp32 GEMM (head / exits only) ----------------
__global__ __launch_bounds__(256) void gemm_f32(
    const float* __restrict__ A, const float* __restrict__ Bm,
    const float* __restrict__ bias, float* __restrict__ C,
    int M, int N, int K)
{
    __shared__ float As[16][68];
    __shared__ float Bs[16][64];
    const int tid = threadIdx.x;
    const int tx = tid & 15, ty = tid >> 4;
    const int m0 = blockIdx.y * 64, n0 = blockIdx.x * 64;
    float acc[4][4] = {};

    for (int k0 = 0; k0 < K; k0 += 16) {
        {
            const int c = tid & 15, r4 = tid >> 4;
#pragma unroll
            for (int i = 0; i < 4; ++i) {
                const int r = r4 + i * 16, gm = m0 + r;
                As[c][r] = (gm < M) ? A[(size_t)gm * K + (k0 + c)] : 0.f;
            }
        }
        {
            const int cb = tid & 63, rb4 = tid >> 6;
#pragma unroll
            for (int i = 0; i < 4; ++i) {
                const int rb = rb4 + i * 4;
                const int gn = n0 + cb;
                Bs[rb][cb] = (gn < N) ? Bm[(size_t)(k0 + rb) * N + gn] : 0.f;
            }
        }
        __syncthreads();
#pragma unroll
        for (int kk = 0; kk < 16; ++kk) {
            const float4 av = *reinterpret_cast<const float4*>(&As[kk][ty * 4]);
            const float4 bv = *reinterpret_cast<const float4*>(&Bs[kk][tx * 4]);
            const float a_[4] = {av.x, av.y, av.z, av.w};
            const float b_[4] = {bv.x, bv.y, bv.z, bv.w};
#pragma unroll
            for (int i2 = 0; i2 < 4; ++i2)
#pragma unroll
                for (int j2 = 0; j2 < 4; ++j2)
                    acc[i2][j2] = fmaf(a_[i2], b_[j2], acc[i2][j2]);
        }
        __syncthreads();
    }

#pragma unroll
    for (int i = 0; i < 4; ++i) {
        const int gm = m0 + ty * 4 + i;
        if (gm >= M) continue;
#pragma unroll
        for (int j = 0; j < 4; ++j) {
            const int gn = n0 + tx * 4 + j;
            if (gn >= N) continue;
            C[(size_t)gm * N + gn] = acc[i][j] + bias[gn];
        }
    }
}

// ---------------- mean over tokens for exits ----------------
__global__ void pool_kernel(const float* __restrict__ h, float* __restrict__ pooled)
{
    const int b = blockIdx.x, e = threadIdx.x;  // block 192
    float s = 0.f;
    for (int n = 0; n < NTOK; ++n) s += h[((size_t)(b * NTOK + n)) * EMB + e];
    pooled[b * EMB + e] = s * (1.f / 197.f);
}

// ---------------- host launch ----------------
extern "C" void kernel_launch(void* const* d_in, const int* in_sizes, int n_in,
                              void* d_out, int out_size, void* d_ws, size_t ws_size,
                              hipStream_t stream)
{
    const float* x          = (const float*)d_in[0];
    const float* patch_w    = (const float*)d_in[1];
    const float* patch_b    = (const float*)d_in[2];
    const float* pe_norm_w  = (const float*)d_in[3];
    const float* pe_norm_b  = (const float*)d_in[4];
    const float* cls_token  = (const float*)d_in[5];
    const float* pos_embed  = (const float*)d_in[6];
    const float* norm1_w    = (const float*)d_in[7];
    const float* norm1_b    = (const float*)d_in[8];
    const float* qkv_w      = (const float*)d_in[9];
    const float* qkv_b      = (const float*)d_in[10];
    const float* proj_mat   = (const float*)d_in[11];
    const float* attn_pw    = (const float*)d_in[12];
    const float* attn_pb    = (const float*)d_in[13];
    const float* norm2_w    = (const float*)d_in[14];
    const float* norm2_b    = (const float*)d_in[15];
    const float* fc1_w      = (const float*)d_in[16];
    const float* fc1_b      = (const float*)d_in[17];
    const float* fc2_w      = (const float*)d_in[18];
    const float* fc2_b      = (const float*)d_in[19];
    const float* exit_w     = (const float*)d_in[20];
    const float* exit_b     = (const float*)d_in[21];
    const float* fnorm_w    = (const float*)d_in[22];
    const float* fnorm_b    = (const float*)d_in[23];
    const float* head_w     = (const float*)d_in[24];
    const float* head_b     = (const float*)d_in[25];
    float* out = (float*)d_out;

    float* ws = (float*)d_ws;
    float* H     = ws + 0;                  // 12608*192 fp32
    u16*   QKVB  = (u16*)(ws + 2420736);    // 12608*576 bf16
    u16*   XLNB  = (u16*)(ws + 6051840);    // 12608*192 bf16
    u16*   KVT   = (u16*)(ws + 19968000);   // 192*64*256 bf16
    u16*   MIDB  = (u16*)(ws + 21540864);   // 12608*768 bf16
    u16*   ATNB  = (u16*)(ws + 26382336);   // 12608*192 bf16
    float* XLNF  = ws + 27592704;           // 64*192
    float* POOL  = ws + 27604992;           // 64*192
    float* KSUM  = ws + 27617280;           // 192*256
    u16*   QKVWT = (u16*)(ws + 27666432);   // 12*576*192 bf16
    u16*   APWT  = (u16*)(ws + 28329984);   // 12*192*192 bf16
    u16*   F1WT  = (u16*)(ws + 28551168);   // 12*768*192 bf16
    u16*   F2WT  = (u16*)(ws + 29435904);   // 12*192*768 bf16
    u16*   PATWB = (u16*)(ws + 30320640);   // 192*768 bf16
    u16*   PMB   = (u16*)(ws + 30394368);   // 12*256*64 bf16
    u16*   P_IMB = MIDB;                    // im2col alias (prologue only)
    float* TOK   = (float*)QKVB;            // patch tokens alias (prologue only)

    if (ws_size < (size_t)30492672 * sizeof(float)) return;

    // ---- weight prep ----
    cvt_bf16<<<(147456 + 255) / 256, 256, 0, stream>>>(patch_w, PATWB, 147456);
    cvt_bf16<<<(196608 + 255) / 256, 256, 0, stream>>>(proj_mat, PMB, 196608);
    tr_bf16<<<(1327104 + 255) / 256, 256, 0, stream>>>(qkv_w,   QKVWT, 192, 576, 1327104);
    tr_bf16<<<(442368 + 255) / 256, 256, 0, stream>>>(attn_pw, APWT,  192, 192, 442368);
    tr_bf16<<<(1769472 + 255) / 256, 256, 0, stream>>>(fc1_w,   F1WT,  192, 768, 1769472);
    tr_bf16<<<(1769472 + 255) / 256, 256, 0, stream>>>(fc2_w,   F2WT,  768, 192, 1769472);

    // ---- patch embed ----
    im2col_kernel<<<(MPAT * 768 + 255) / 256, 256, 0, stream>>>(x, P_IMB, MPAT * 768);
    gemm_bf16<<<dim3(3, 98), 256, 0, stream>>>(P_IMB, PATWB, patch_b,
                                               TOK, nullptr, MPAT, EMB, 768, 0);
    embed_finish<<<(MTOT + 3) / 4, 256, 0, stream>>>(TOK, cls_token, pos_embed,
                                                     pe_norm_w, pe_norm_b, H);
    ln192<<<(MTOT + 3) / 4, 256, 0, stream>>>(H, EMB, norm1_w, norm1_b,
                                              XLNB, nullptr, MTOT);

    // ---- transformer layers ----
    for (int i = 0; i < 12; ++i) {
        const u16* qwt  = QKVWT + (size_t)i * 576 * 192;
        const u16* pwt  = APWT  + (size_t)i * 192 * 192;
        const u16* f1wt = F1WT  + (size_t)i * 768 * 192;
        const u16* f2wt = F2WT  + (size_t)i * 192 * 768;
        const u16* pmb  = PMB   + (size_t)i * 256 * 64;
        const float* qb  = qkv_b   + (size_t)i * 576;
        const float* pb  = attn_pb + (size_t)i * 192;
        const float* f1b = fc1_b   + (size_t)i * 768;
        const float* f2b = fc2_b   + (size_t)i * 192;

        gemm_bf16<<<dim3(9, 99), 256, 0, stream>>>(XLNB, qwt, qb,
                                                   nullptr, QKVB, MTOT, 576, 192, 3);
        attn_pkv<<<dim3(BHT), 256, 0, stream>>>(QKVB, pmb, KVT, KSUM);
        attn_out<<<dim3(4, BHT), 256, 0, stream>>>(QKVB, pmb, KVT, KSUM, ATNB);
        // proj + bias + residual -> H ; LN(norm2) -> XLNB, fused
        gemm_ln<<<197, 256, 0, stream>>>(ATNB, pwt, pb,
                                         norm2_w + (size_t)i * EMB, norm2_b + (size_t)i * EMB,
                                         H, XLNB, EMB);
        gemm_bf16<<<dim3(12, 99), 256, 0, stream>>>(XLNB, f1wt, f1b,
                                                    nullptr, MIDB, MTOT, MLPD, 192, 2);
        // fc2 + bias + residual -> H ; LN(norm1 of next layer) -> XLNB, fused
        const float* nw = (i < 11) ? norm1_w + (size_t)(i + 1) * EMB : nullptr;
        const float* nb = (i < 11) ? norm1_b + (size_t)(i + 1) * EMB : nullptr;
        gemm_ln<<<197, 256, 0, stream>>>(MIDB, f2wt, f2b, nw, nb, H, XLNB, MLPD);

        const int e = (i == 3) ? 0 : (i == 7) ? 1 : (i == 11) ? 2 : -1;
        if (e >= 0) {
            pool_kernel<<<BB, 192, 0, stream>>>(H, POOL);
            gemm_f32<<<dim3(16, 1), 256, 0, stream>>>(POOL, exit_w + (size_t)e * 192 * 1000,
                                                      exit_b + (size_t)e * 1000,
                                                      out + (size_t)(1 + e) * BB * NCLS,
                                                      BB, NCLS, EMB);
        }
    }

    // ---- head ----
    ln192<<<(BB + 3) / 4, 256, 0, stream>>>(H, NTOK * EMB, fnorm_w, fnorm_b,
                                            nullptr, XLNF, BB);
    gemm_f32<<<dim3(16, 1), 256, 0, stream>>>(XLNF, head_w, head_b, out, BB, NCLS, EMB);
}